// Round 4
// baseline (334.429 us; speedup 1.0000x reference)
//
#include <hip/hip_runtime.h>
#include <stdint.h>

#define NB 8
#define NC 256
#define NHW 4096
#define NG 32
#define GELEMS (8*NHW)
#define EPS 1e-5f

typedef unsigned short u16;
typedef unsigned int u32;
typedef __attribute__((ext_vector_type(8))) short bf16x8;
typedef __attribute__((ext_vector_type(4))) float f32x4;

__device__ __forceinline__ float bf2f(u16 u){ return __uint_as_float((u32)u << 16); }
__device__ __forceinline__ u16 f2bf(float f){
  u32 i = __float_as_uint(f);
  u32 r = i + 0x7fffu + ((i >> 16) & 1u);   // RNE
  return (u16)(r >> 16);
}
__device__ __forceinline__ u32 pack2(float a, float b){
  return (u32)f2bf(a) | ((u32)f2bf(b) << 16);
}

#define GLD16(g, l) __builtin_amdgcn_global_load_lds( \
    (const __attribute__((address_space(1))) u32*)(g), \
    (__attribute__((address_space(3))) u32*)(l), 16, 0, 0)

// ---------------- GroupNorm statistics: one block per (b,g) ----------------
__global__ __launch_bounds__(256) void gn_stats_k(const float* __restrict__ x,
                                                  float* __restrict__ stats){
  int bg = blockIdx.x;
  const float* xp = x + (size_t)bg * GELEMS;
  float s = 0.f, s2 = 0.f;
  for (int i = threadIdx.x * 4; i < GELEMS; i += 256 * 4) {
    float4 v = *(const float4*)(xp + i);
    s  += v.x + v.y + v.z + v.w;
    s2 += v.x*v.x + v.y*v.y + v.z*v.z + v.w*v.w;
  }
  #pragma unroll
  for (int off = 32; off; off >>= 1) { s += __shfl_xor(s, off); s2 += __shfl_xor(s2, off); }
  __shared__ float rs[4], rs2[4];
  int w = threadIdx.x >> 6;
  if ((threadIdx.x & 63) == 0) { rs[w] = s; rs2[w] = s2; }
  __syncthreads();
  if (threadIdx.x == 0) {
    float ts = rs[0]+rs[1]+rs[2]+rs[3], t2 = rs2[0]+rs2[1]+rs2[2]+rs2[3];
    float mean = ts * (1.f/GELEMS);
    float var  = t2 * (1.f/GELEMS) - mean*mean;
    stats[2*bg]   = mean;
    stats[2*bg+1] = rsqrtf(var + EPS);
  }
}

__global__ __launch_bounds__(256) void gn_coef_k(const float* __restrict__ stats,
                                                 const float* __restrict__ gamma,
                                                 const float* __restrict__ beta,
                                                 float* __restrict__ coef){
  int i = blockIdx.x * 256 + threadIdx.x;
  if (i >= NB*NC) return;
  int b = i >> 8, c = i & 255;
  float mean = stats[2*(b*NG + (c>>3))];
  float rstd = stats[2*(b*NG + (c>>3)) + 1];
  float sc = gamma[c] * rstd;
  coef[2*i]   = sc;
  coef[2*i+1] = beta[c] - mean * sc;
}

__global__ __launch_bounds__(256) void cvtw_k(const float* __restrict__ w,
                                              u16* __restrict__ wbf){
  int i = blockIdx.x * 256 + threadIdx.x;
  wbf[i] = f2bf(w[i]);
}

// -------- MFMA fused GN + QKV: Q,K -> [n][c] bf16 (Q pre-scaled), V -> [c][n] --------
__global__ __launch_bounds__(256, 2) void qkv_mfma_k(const float* __restrict__ x,
    const float* __restrict__ coef, const u16* __restrict__ wqbf,
    const float* __restrict__ b_qkv,
    u16* __restrict__ qT, u16* __restrict__ kT, u16* __restrict__ vS){
  __shared__ u16 Wbuf[2][4096];              // [16][256] bf16, chunk^=(row&7)

  int bid = blockIdx.x;
  int wg = ((bid & 7) << 6) | (bid >> 3);    // XCD swizzle: batch b -> XCD b
  int b  = wg >> 6;
  int n0 = (wg & 63) << 6;
  int w = threadIdx.x >> 6, lane = threadIdx.x & 63;
  int lo = lane & 15, g = lane >> 4;
  int n = n0 + w*16 + lo;

  int row1 = w*2 + (lane >> 5);
  int sxor = ((lane & 31) ^ (row1 & 7)) * 8;
  int src1 = row1 * 256 + sxor;
  int src2 = (row1 + 8) * 256 + sxor;

  auto STAGE = [&](int bufi, int ot) {
    const u16* src = wqbf + ot * 4096;
    GLD16(src + src1, &Wbuf[bufi][w * 512]);
    GLD16(src + src2, &Wbuf[bufi][2048 + w * 512]);
  };

  STAGE(0, 0);

  bf16x8 hf[8];
  {
    const float* xb = x + (size_t)b * NC * NHW + n;
    const float* cf = coef + b * 512;
    #pragma unroll
    for (int kc = 0; kc < 8; ++kc) {
      union { u32 u[4]; bf16x8 v; } hu;
      #pragma unroll
      for (int p = 0; p < 4; ++p) {
        int c = kc*32 + g*8 + p*2;
        float2 s0 = *(const float2*)(cf + 2*c);
        float2 s1 = *(const float2*)(cf + 2*c + 2);
        float f0 = xb[(size_t)c * NHW]     * s0.x + s0.y;
        float f1 = xb[(size_t)(c+1) * NHW] * s1.x + s1.y;
        hu.u[p] = pack2(f0, f1);
      }
      hf[kc] = hu.v;
    }
  }

  u16* qrow = qT + ((size_t)(b * NHW + n)) * NC;
  u16* krow = kT + ((size_t)(b * NHW + n)) * NC;

  for (int ot = 0; ot < 48; ++ot) {
    __syncthreads();
    if (ot < 47) STAGE((ot + 1) & 1, ot + 1);
    const u16* Wl = Wbuf[ot & 1];
    int sw = lo & 7;
    f32x4 acc = (f32x4){0.f, 0.f, 0.f, 0.f};

    if (ot < 32) {
      #pragma unroll
      for (int kc = 0; kc < 8; ++kc) {
        bf16x8 wf = *(const bf16x8*)(Wl + lo*256 + ((kc*4 + g) ^ sw) * 8);
        acc = __builtin_amdgcn_mfma_f32_16x16x32_bf16(wf, hf[kc], acc, 0, 0, 0);
      }
      float4 bq = *(const float4*)(b_qkv + ot*16 + 4*g);
      float v0 = acc[0]+bq.x, v1 = acc[1]+bq.y, v2 = acc[2]+bq.z, v3 = acc[3]+bq.w;
      if (ot < 16) {
        v0 *= 0.0625f; v1 *= 0.0625f; v2 *= 0.0625f; v3 *= 0.0625f;
        uint2 st = { pack2(v0, v1), pack2(v2, v3) };
        *(uint2*)(qrow + ot*16 + 4*g) = st;
      } else {
        uint2 st = { pack2(v0, v1), pack2(v2, v3) };
        *(uint2*)(krow + (ot-16)*16 + 4*g) = st;
      }
    } else {
      #pragma unroll
      for (int kc = 0; kc < 8; ++kc) {
        bf16x8 wf = *(const bf16x8*)(Wl + lo*256 + ((kc*4 + g) ^ sw) * 8);
        acc = __builtin_amdgcn_mfma_f32_16x16x32_bf16(hf[kc], wf, acc, 0, 0, 0);
      }
      int oc = (ot - 32) * 16 + lo;
      float bv = b_qkv[512 + oc];
      uint2 st = { pack2(acc[0]+bv, acc[1]+bv), pack2(acc[2]+bv, acc[3]+bv) };
      *(uint2*)(vS + ((size_t)(b * NC + oc)) * NHW + n0 + w*16 + 4*g) = st;
    }
  }
}

// ---------------- scalar qkv fallback ----------------
__global__ __launch_bounds__(256) void qkv_scalar_k(const float* __restrict__ x,
                                             const float* __restrict__ coef,
                                             const float* __restrict__ w_qkv,
                                             const float* __restrict__ b_qkv,
                                             u16* __restrict__ qT, u16* __restrict__ kT,
                                             u16* __restrict__ vS){
  int idx0 = blockIdx.x;
  int idx = (idx0 >> 3) + (idx0 & 7) * 768;
  int og = idx % 48;
  int t  = idx / 48;
  int nc = t & 15;
  int b  = t >> 4;
  int n  = nc * 256 + threadIdx.x;
  const float* xb = x + (size_t)b * NC * NHW + n;
  const float* cf = coef + b * NC * 2;
  int ob = og * 16;
  float acc[16];
  #pragma unroll
  for (int j = 0; j < 16; ++j) acc[j] = b_qkv[ob + j];
  for (int c = 0; c < NC; ++c) {
    float h = xb[(size_t)c * NHW] * cf[2*c] + cf[2*c+1];
    const float* wr = w_qkv + (size_t)ob * NC + c;
    #pragma unroll
    for (int j = 0; j < 16; ++j) acc[j] += h * wr[(size_t)j * NC];
  }
  if (ob < 512) {
    float sc = (ob < 256) ? 0.0625f : 1.0f;
    union { u16 h[16]; uint4 q[2]; } u;
    #pragma unroll
    for (int j = 0; j < 16; ++j) u.h[j] = f2bf(acc[j] * sc);
    u16* p = (ob < 256) ? (qT + ((size_t)(b*NHW + n))*NC + ob)
                        : (kT + ((size_t)(b*NHW + n))*NC + (ob - 256));
    *(uint4*)p = u.q[0];
    *(uint4*)(p + 8) = u.q[1];
  } else {
    u16* p = vS + ((size_t)(b*NC) + (ob - 512)) * NHW + n;
    #pragma unroll
    for (int j = 0; j < 16; ++j) p[(size_t)j * NHW] = f2bf(acc[j]);
  }
}

// ---------------- MFMA flash attention, NT=2, dbuf staging, 1 block/CU ----------------
// 4 waves x 32 q-rows = 128 rows/block; KVBLK=64; swapped QK^T; fused proj+residual.
template<int WBF>
__global__ __launch_bounds__(256, 1) void attn_k(const float* __restrict__ x,
    const u16* __restrict__ qT, const u16* __restrict__ kT, const u16* __restrict__ vS,
    const float* __restrict__ w_proj, const u16* __restrict__ wbf,
    const float* __restrict__ b_proj, float* __restrict__ out){
  __shared__ char smem[147456];
  // buf i (i=0,1): K at i*65536 ([64][256] bf16, chunk^=(row&7)), V at i*65536+32768
  // P at 131072 + w*4096 ([32][64] bf16, swizzled). Epilogue: O bf16 [4][32][264] at 0.

  int bid = blockIdx.x;
  int wg = ((bid & 7) << 5) | (bid >> 3);   // XCD swizzle (256 = 8*32, bijective)
  int b  = wg >> 5;
  int n0 = (wg & 31) << 7;
  int w = threadIdx.x >> 6, lane = threadIdx.x & 63;
  int lo = lane & 15, g = lane >> 4;
  int sw = lo & 7;

  const u16* qTb = qT + (size_t)b * NHW * NC;
  const u16* kTb = kT + (size_t)b * NHW * NC;
  const u16* vSb = vS + (size_t)b * NC * NHW;

  // Q fragments (stationary): rows n0 + w*32 + nt*16 + lo
  bf16x8 qf[2][8];
  #pragma unroll
  for (int nt = 0; nt < 2; ++nt) {
    const u16* qp = qTb + (size_t)(n0 + w*32 + nt*16 + lo) * NC + g*8;
    #pragma unroll
    for (int kc = 0; kc < 8; ++kc) qf[nt][kc] = *(const bf16x8*)(qp + kc*32);
  }

  // staging addresses: linear LDS dest, inverse-swizzled global source
  int koff[8], voff[8];
  #pragma unroll
  for (int i = 0; i < 8; ++i) {
    int o = w*8192 + i*1024 + lane*16;
    int mr = o >> 9;
    int kch = ((o >> 4) & 31) ^ (mr & 7);
    koff[i] = mr*NC + kch*8;
    int cr = o >> 7;
    int vch = ((o >> 4) & 7) ^ (cr & 7);
    voff[i] = cr*NHW + vch*8;
  }

  // prologue stage tile 0 into buf 0
  {
    const u16* kp = kTb;
    const u16* vp = vSb;
    #pragma unroll
    for (int i = 0; i < 8; ++i) {
      GLD16(kp + koff[i], smem + w*8192 + i*1024);
      GLD16(vp + voff[i], smem + 32768 + w*8192 + i*1024);
    }
  }

  f32x4 oacc[2][16];
  #pragma unroll
  for (int nt = 0; nt < 2; ++nt)
    #pragma unroll
    for (int i = 0; i < 16; ++i) oacc[nt][i] = (f32x4){0.f,0.f,0.f,0.f};
  float mrun[2] = {-1e30f, -1e30f}, lrun[2] = {0.f, 0.f};

  char* Pw = smem + 131072 + w*4096;

  __syncthreads();                            // tile 0 staged

  for (int it = 0; it < 64; ++it) {
    int cur = it & 1;
    if (it < 63) {                            // overlap next-tile staging with compute
      const u16* kp = kTb + (size_t)((it+1) * 64) * NC;
      const u16* vp = vSb + (it+1) * 64;
      char* dst = smem + (cur ^ 1) * 65536;
      #pragma unroll
      for (int i = 0; i < 8; ++i) {
        GLD16(kp + koff[i], dst + w*8192 + i*1024);
        GLD16(vp + voff[i], dst + 32768 + w*8192 + i*1024);
      }
    }
    const u16* Klds = (const u16*)(smem + cur * 65536);
    const u16* Vlds = (const u16*)(smem + cur * 65536 + 32768);

    // swapped QK^T: st[nt][mt], rows m = mt*16+4g+r, col n = nt*16+lo
    f32x4 st[2][4];
    #pragma unroll
    for (int nt = 0; nt < 2; ++nt)
      #pragma unroll
      for (int mt = 0; mt < 4; ++mt) st[nt][mt] = (f32x4){0.f,0.f,0.f,0.f};
    #pragma unroll
    for (int kc = 0; kc < 8; ++kc) {
      int ch = (kc*4 + g) ^ sw;
      #pragma unroll
      for (int mt = 0; mt < 4; ++mt) {
        bf16x8 kf = *(const bf16x8*)(Klds + (mt*16 + lo)*NC + ch*8);
        st[0][mt] = __builtin_amdgcn_mfma_f32_16x16x32_bf16(kf, qf[0][kc], st[0][mt], 0, 0, 0);
        st[1][mt] = __builtin_amdgcn_mfma_f32_16x16x32_bf16(kf, qf[1][kc], st[1][mt], 0, 0, 0);
      }
    }

    // online softmax per nt (row n lane-local: 16 in-lane + 2 shuffles)
    float pmax[2];
    #pragma unroll
    for (int nt = 0; nt < 2; ++nt) {
      float pm = -1e30f;
      #pragma unroll
      for (int mt = 0; mt < 4; ++mt)
        #pragma unroll
        for (int r = 0; r < 4; ++r) pm = fmaxf(pm, st[nt][mt][r]);
      pm = fmaxf(pm, __shfl_xor(pm, 16));
      pm = fmaxf(pm, __shfl_xor(pm, 32));
      pmax[nt] = pm;
    }

    if (!__all(pmax[0] - mrun[0] <= 8.f && pmax[1] - mrun[1] <= 8.f)) {
      #pragma unroll
      for (int nt = 0; nt < 2; ++nt) {
        float mnew = fmaxf(mrun[nt], pmax[nt]);
        float corr = __expf(mrun[nt] - mnew);
        mrun[nt] = mnew;
        lrun[nt] *= corr;
        float c0 = __shfl(corr, 4*g+0), c1 = __shfl(corr, 4*g+1);
        float c2 = __shfl(corr, 4*g+2), c3 = __shfl(corr, 4*g+3);
        #pragma unroll
        for (int ct = 0; ct < 16; ++ct) {
          oacc[nt][ct][0] *= c0; oacc[nt][ct][1] *= c1;
          oacc[nt][ct][2] *= c2; oacc[nt][ct][3] *= c3;
        }
      }
    }

    #pragma unroll
    for (int nt = 0; nt < 2; ++nt) {
      float psum = 0.f;
      #pragma unroll
      for (int mt = 0; mt < 4; ++mt) {
        float p0 = __expf(st[nt][mt][0] - mrun[nt]);
        float p1 = __expf(st[nt][mt][1] - mrun[nt]);
        float p2 = __expf(st[nt][mt][2] - mrun[nt]);
        float p3 = __expf(st[nt][mt][3] - mrun[nt]);
        psum += (p0 + p1) + (p2 + p3);
        uint2 pk = { pack2(p0, p1), pack2(p2, p3) };
        *(uint2*)(Pw + (nt*16 + lo)*128 + ((((2*mt + (g>>1)) ^ sw)) << 4) + ((g&1) << 3)) = pk;
      }
      psum += __shfl_xor(psum, 16);
      psum += __shfl_xor(psum, 32);
      lrun[nt] += psum;
    }

    // PV: A = P rows (nt*16+lo), B = V[m][c]; vf reused across nt
    #pragma unroll
    for (int ks = 0; ks < 2; ++ks) {
      bf16x8 pa0 = *(const bf16x8*)(Pw + (0*16 + lo)*128 + (((ks*4 + g) ^ sw) << 4));
      bf16x8 pa1 = *(const bf16x8*)(Pw + (1*16 + lo)*128 + (((ks*4 + g) ^ sw) << 4));
      int ch = (ks*4 + g) ^ sw;
      #pragma unroll
      for (int ct = 0; ct < 16; ++ct) {
        bf16x8 vf = *(const bf16x8*)(Vlds + (ct*16 + lo)*64 + ch*8);
        oacc[0][ct] = __builtin_amdgcn_mfma_f32_16x16x32_bf16(pa0, vf, oacc[0][ct], 0, 0, 0);
        oacc[1][ct] = __builtin_amdgcn_mfma_f32_16x16x32_bf16(pa1, vf, oacc[1][ct], 0, 0, 0);
      }
    }
    __syncthreads();                          // drains next-stage vmcnt + syncs buffers
  }

  // ---------------- epilogue: O -> LDS bf16 [32][264]/wave, proj MFMA, residual ----------------
  u16* Ol = (u16*)smem + w * 8448;            // 32 rows x 264, 16896 B/wave
  #pragma unroll
  for (int nt = 0; nt < 2; ++nt) {
    float linv = 1.f / lrun[nt];
    float l0 = __shfl(linv, 4*g+0), l1 = __shfl(linv, 4*g+1);
    float l2 = __shfl(linv, 4*g+2), l3 = __shfl(linv, 4*g+3);
    #pragma unroll
    for (int ct = 0; ct < 16; ++ct) {
      int col = ct*16 + lo;
      Ol[(nt*16 + 4*g+0)*264 + col] = f2bf(oacc[nt][ct][0] * l0);
      Ol[(nt*16 + 4*g+1)*264 + col] = f2bf(oacc[nt][ct][1] * l1);
      Ol[(nt*16 + 4*g+2)*264 + col] = f2bf(oacc[nt][ct][2] * l2);
      Ol[(nt*16 + 4*g+3)*264 + col] = f2bf(oacc[nt][ct][3] * l3);
    }
  }

  #pragma unroll
  for (int pt = 0; pt < 2; ++pt) {
    f32x4 pacc[16];
    #pragma unroll
    for (int i = 0; i < 16; ++i) pacc[i] = (f32x4){0.f,0.f,0.f,0.f};
    #pragma unroll
    for (int ks = 0; ks < 8; ++ks) {
      bf16x8 af = *(const bf16x8*)(Ol + (pt*16 + lo)*264 + ks*32 + g*8);
      #pragma unroll
      for (int ot = 0; ot < 16; ++ot) {
        bf16x8 bf;
        if (WBF) {
          bf = *(const bf16x8*)(wbf + (size_t)(ot*16 + lo)*NC + ks*32 + g*8);
        } else {
          const float* wp = w_proj + (size_t)(ot*16 + lo)*NC + ks*32 + g*8;
          float4 b0 = *(const float4*)wp;
          float4 b1 = *(const float4*)(wp + 4);
          union { u16 h[8]; bf16x8 v; } bu;
          bu.h[0]=f2bf(b0.x); bu.h[1]=f2bf(b0.y); bu.h[2]=f2bf(b0.z); bu.h[3]=f2bf(b0.w);
          bu.h[4]=f2bf(b1.x); bu.h[5]=f2bf(b1.y); bu.h[6]=f2bf(b1.z); bu.h[7]=f2bf(b1.w);
          bf = bu.v;
        }
        pacc[ot] = __builtin_amdgcn_mfma_f32_16x16x32_bf16(af, bf, pacc[ot], 0, 0, 0);
      }
    }
    int nrow = n0 + w*32 + pt*16 + 4*g;
    #pragma unroll
    for (int ot = 0; ot < 16; ++ot) {
      int o = ot*16 + lo;
      float bp = b_proj[o];
      size_t base = ((size_t)(b*NC + o)) * NHW + nrow;
      float4 xr = *(const float4*)(x + base);
      float4 ov = { pacc[ot][0] + bp + xr.x, pacc[ot][1] + bp + xr.y,
                    pacc[ot][2] + bp + xr.z, pacc[ot][3] + bp + xr.w };
      *(float4*)(out + base) = ov;
    }
  }
}

extern "C" void kernel_launch(void* const* d_in, const int* in_sizes, int n_in,
                              void* d_out, int out_size, void* d_ws, size_t ws_size,
                              hipStream_t stream) {
  const float* x      = (const float*)d_in[0];
  const float* gamma  = (const float*)d_in[1];
  const float* beta   = (const float*)d_in[2];
  const float* w_qkv  = (const float*)d_in[3];
  const float* b_qkv  = (const float*)d_in[4];
  const float* w_proj = (const float*)d_in[5];
  const float* b_proj = (const float*)d_in[6];
  float* out = (float*)d_out;

  float* stats = (float*)d_ws;                        // 512 f
  float* coef  = stats + 2 * NB * NG;                 // 4096 f
  u16* qT = (u16*)((char*)d_ws + 18432);              // [b][n][c] 16MB
  u16* kT = qT + (size_t)NB * NHW * NC;               // [b][n][c] 16MB
  u16* vS = kT + (size_t)NB * NHW * NC;               // [b][c][n] 16MB
  u16* wbf  = vS + (size_t)NB * NC * NHW;             // proj W bf16, 128KB
  u16* wqbf = wbf + NC * NC;                          // qkv W bf16, 384KB
  size_t need = 18432 + (size_t)3 * NB * NHW * NC * 2
              + (size_t)NC * NC * 2 + (size_t)3 * NC * NC * 2;

  gn_stats_k<<<NB * NG, 256, 0, stream>>>(x, stats);
  gn_coef_k<<<(NB * NC + 255) / 256, 256, 0, stream>>>(stats, gamma, beta, coef);
  if (ws_size >= need) {
    cvtw_k<<<NC * NC / 256, 256, 0, stream>>>(w_proj, wbf);
    cvtw_k<<<3 * NC * NC / 256, 256, 0, stream>>>(w_qkv, wqbf);
    qkv_mfma_k<<<512, 256, 0, stream>>>(x, coef, wqbf, b_qkv, qT, kT, vS);
    attn_k<1><<<256, 256, 0, stream>>>(x, qT, kT, vS, w_proj, wbf, b_proj, out);
  } else {
    qkv_scalar_k<<<NB * 16 * 48, 256, 0, stream>>>(x, coef, w_qkv, b_qkv, qT, kT, vS);
    attn_k<0><<<256, 256, 0, stream>>>(x, qT, kT, vS, w_proj, wbf, b_proj, out);
  }
}